// Round 4
// baseline (370.004 us; speedup 1.0000x reference)
//
#include <hip/hip_runtime.h>
#include <hip/hip_bf16.h>

#define NB 100
#define NT 500
#define CIN 300
#define COUT 500
#define M_TOT (NB * NT)   // 50000

constexpr int BM = 128, BN = 128, BK = 16;
constexpr int LDA = BM + 4;                  // 132: float4-aligned rows, odd-ish bank stride
constexpr int NSTEP = (CIN + BK - 1) / BK;   // 19 (K padded 300->304 with zeros)

// C[m][o] = sum_k X[m][k] * W[o][k]   (X: [M,300], W: [500,300], C: [M,500])
__global__ __launch_bounds__(256) void gemm_f32(
    const float* __restrict__ X, const float* __restrict__ W, float* __restrict__ C)
{
    __shared__ float As[2][BK][LDA];   // 2 x 16.9 KB
    __shared__ float Bs[2][BK][LDA];   // total 33.8 KB -> 4 blocks/CU

    const int ntiles_n = (COUT + BN - 1) / BN;  // 4
    const int mtile = blockIdx.x / ntiles_n;    // ntile fastest: 4 consecutive blocks share X tile
    const int ntile = blockIdx.x % ntiles_n;
    const int m0 = mtile * BM, n0 = ntile * BN;

    const int tid  = threadIdx.x;
    const int lane = tid & 63;
    const int wid  = tid >> 6;              // 4 waves: 2x2 grid of 64x64 wave tiles
    const int wmb  = (wid >> 1) << 6;       // 0 or 64
    const int wnb  = (wid & 1) << 6;        // 0 or 64
    const int r4   = (lane >> 3) << 2;      // 0,4,...,28
    const int c4   = (lane & 7) << 2;       // 0,4,...,28

    // staging: 2 lanes per row, each lane two float4 along k (quads qa0, qa0+1)
    const int srow = tid >> 1;              // 0..127
    const int sq0  = (tid & 1) * 2;         // quad 0 or 2 (covers k-offsets sq0*4 .. sq0*4+7)

    const int mr = min(m0 + srow, M_TOT - 1);
    const int orr = min(n0 + srow, COUT - 1);
    const float* xp = X + (size_t)mr * CIN;
    const float* wp = W + (size_t)orr * CIN;

    auto ldq = [](const float* p, int kk) -> float4 {
        return (kk < CIN) ? *(const float4*)(p + kk) : make_float4(0.f, 0.f, 0.f, 0.f);
    };

    float acc[8][8];
    #pragma unroll
    for (int i = 0; i < 8; ++i)
        #pragma unroll
        for (int j = 0; j < 8; ++j) acc[i][j] = 0.f;

    // ---- prologue: load + write tile 0 ----
    float4 xa0 = ldq(xp, sq0 * 4);
    float4 xa1 = ldq(xp, sq0 * 4 + 4);
    float4 wb0 = ldq(wp, sq0 * 4);
    float4 wb1 = ldq(wp, sq0 * 4 + 4);

    #define WRITE_TILE(buf)                                                     \
        do {                                                                    \
            As[buf][sq0 * 4 + 0][srow] = xa0.x; As[buf][sq0 * 4 + 1][srow] = xa0.y; \
            As[buf][sq0 * 4 + 2][srow] = xa0.z; As[buf][sq0 * 4 + 3][srow] = xa0.w; \
            As[buf][sq0 * 4 + 4][srow] = xa1.x; As[buf][sq0 * 4 + 5][srow] = xa1.y; \
            As[buf][sq0 * 4 + 6][srow] = xa1.z; As[buf][sq0 * 4 + 7][srow] = xa1.w; \
            Bs[buf][sq0 * 4 + 0][srow] = wb0.x; Bs[buf][sq0 * 4 + 1][srow] = wb0.y; \
            Bs[buf][sq0 * 4 + 2][srow] = wb0.z; Bs[buf][sq0 * 4 + 3][srow] = wb0.w; \
            Bs[buf][sq0 * 4 + 4][srow] = wb1.x; Bs[buf][sq0 * 4 + 5][srow] = wb1.y; \
            Bs[buf][sq0 * 4 + 6][srow] = wb1.z; Bs[buf][sq0 * 4 + 7][srow] = wb1.w; \
        } while (0)

    WRITE_TILE(0);
    __syncthreads();

    int cur = 0;
    for (int step = 0; step < NSTEP; ++step) {
        // issue next tile's loads immediately; latency hides under this step's FMAs
        if (step + 1 < NSTEP) {
            const int kn = (step + 1) * BK + sq0 * 4;
            xa0 = ldq(xp, kn);
            xa1 = ldq(xp, kn + 4);
            wb0 = ldq(wp, kn);
            wb1 = ldq(wp, kn + 4);
        }

        #pragma unroll
        for (int k = 0; k < BK; ++k) {
            // each read: 8 unique contiguous addrs x 16B = all 32 banks once, 8-lane broadcast
            float4 a0 = *(const float4*)&As[cur][k][wmb + r4];
            float4 a1 = *(const float4*)&As[cur][k][wmb + 32 + r4];
            float4 b0 = *(const float4*)&Bs[cur][k][wnb + c4];
            float4 b1 = *(const float4*)&Bs[cur][k][wnb + 32 + c4];
            float a[8] = {a0.x, a0.y, a0.z, a0.w, a1.x, a1.y, a1.z, a1.w};
            float b[8] = {b0.x, b0.y, b0.z, b0.w, b1.x, b1.y, b1.z, b1.w};
            #pragma unroll
            for (int i = 0; i < 8; ++i)
                #pragma unroll
                for (int j = 0; j < 8; ++j)
                    acc[i][j] += a[i] * b[j];
        }

        if (step + 1 < NSTEP) {
            WRITE_TILE(cur ^ 1);   // other buffer: safe, its readers finished last step
            __syncthreads();       // single barrier per step
            cur ^= 1;
        }
    }

    // epilogue: rows m0+wmb+{h*32+r4+i}, cols n0+wnb+{c4.., 32+c4..}
    #pragma unroll
    for (int h = 0; h < 2; ++h) {
        #pragma unroll
        for (int i = 0; i < 4; ++i) {
            const int m = m0 + wmb + h * 32 + r4 + i;
            if (m >= M_TOT) continue;
            float* cp = C + (size_t)m * COUT;
            const int col0 = n0 + wnb + c4;        // COUT%4==0: float4s never straddle the edge
            const int col1 = col0 + 32;
            const int ai = h * 4 + i;
            if (col0 < COUT)
                *(float4*)(cp + col0) = make_float4(acc[ai][0], acc[ai][1], acc[ai][2], acc[ai][3]);
            if (col1 < COUT)
                *(float4*)(cp + col1) = make_float4(acc[ai][4], acc[ai][5], acc[ai][6], acc[ai][7]);
        }
    }
    #undef WRITE_TILE
}

// In-place LIF scan over t for each neuron n = b*COUT + o. threshold == 1.
__global__ __launch_bounds__(256) void lif_scan(
    const float* __restrict__ alpha, float* __restrict__ C)
{
    const int n = blockIdx.x * blockDim.x + threadIdx.x;
    if (n >= NB * COUT) return;
    const int b = n / COUT, o = n % COUT;
    const float a = alpha[n];
    float v = 0.f;
    float* p = C + (size_t)b * NT * COUT + o;

    constexpr int U = 10;   // 500 = 50 * 10
    for (int t0 = 0; t0 < NT; t0 += U) {
        float xl[U];
        #pragma unroll
        for (int u = 0; u < U; ++u) xl[u] = p[(size_t)(t0 + u) * COUT];
        float s[U];
        #pragma unroll
        for (int u = 0; u < U; ++u) {
            float vp = a * v + xl[u];
            vp = fmaxf(vp, -1.f);
            float sp = (vp >= 1.f) ? floorf(vp) : 0.f;
            v = vp - sp;
            s[u] = sp;
        }
        #pragma unroll
        for (int u = 0; u < U; ++u) p[(size_t)(t0 + u) * COUT] = s[u];
    }
}

extern "C" void kernel_launch(void* const* d_in, const int* in_sizes, int n_in,
                              void* d_out, int out_size, void* d_ws, size_t ws_size,
                              hipStream_t stream) {
    const float* X     = (const float*)d_in[0];   // [100,500,300]
    const float* W     = (const float*)d_in[1];   // [500,300]
    const float* alpha = (const float*)d_in[2];   // [50000]
    float* C = (float*)d_out;                     // [100,500,500]

    const int mtiles = (M_TOT + BM - 1) / BM;     // 391
    const int ntiles = (COUT + BN - 1) / BN;      // 4
    gemm_f32<<<dim3(mtiles * ntiles), dim3(256), 0, stream>>>(X, W, C);

    const int nneur = NB * COUT;                  // 50000
    lif_scan<<<dim3((nneur + 255) / 256), dim3(256), 0, stream>>>(alpha, C);
}

// Round 8
// 293.787 us; speedup vs baseline: 1.2594x; 1.2594x over previous
//
#include <hip/hip_runtime.h>
#include <hip/hip_bf16.h>
#include <stdint.h>

#define NB 100
#define NT 500
#define CIN 300
#define COUT 500
#define M_TOT (NB * NT)       // 50000
#define MTILES 391            // ceil(50000/128)
#define NTILES 4              // 512/128
#define KTILES 10             // 320/32
#define NPANEL (MTILES * KTILES + NTILES * KTILES)   // 3950 panels of 4096 floats
#define WS_NEED ((size_t)NPANEL * 4096 * 4)          // 64,716,800 B

__device__ __forceinline__ void gload_lds16(const void* g, void* l) {
    __builtin_amdgcn_global_load_lds(
        (const __attribute__((address_space(1))) unsigned int*)g,
        (__attribute__((address_space(3))) unsigned int*)l,
        16, 0, 0);
}

// ---- pre-transpose X,W into panelized [panel][32 kk][128 m] f32 tiles (zero-padded) ----
// X panels: pid = mtile*10 + kt (3910), then W panels: pid = 3910 + ntile*10 + kt (40).
__global__ __launch_bounds__(256) void split_t(
    const float* __restrict__ X, const float* __restrict__ W, float* __restrict__ ws)
{
    const int bid = blockIdx.x;
    const int tid = threadIdx.x;
    const float* src; int rowbase, nrows, kt;
    if (bid < MTILES * KTILES) {
        src = X; rowbase = (bid / KTILES) * 128; nrows = M_TOT; kt = bid % KTILES;
    } else {
        const int w = bid - MTILES * KTILES;
        src = W; rowbase = (w / KTILES) * 128; nrows = COUT; kt = w % KTILES;
    }
    const int kk = tid >> 3;            // 0..31
    const int m0 = (tid & 7) * 16;      // 0..112
    const int k  = kt * 32 + kk;

    float v[16];
    #pragma unroll
    for (int j = 0; j < 16; ++j) {
        const int row = rowbase + m0 + j;
        v[j] = (row < nrows && k < CIN) ? src[(size_t)row * CIN + k] : 0.f;
    }
    float* out = ws + (size_t)bid * 4096 + (size_t)kk * 128 + m0;
    #pragma unroll
    for (int c = 0; c < 4; ++c)
        *(float4*)(out + c * 4) = make_float4(v[c*4], v[c*4+1], v[c*4+2], v[c*4+3]);
}

// ---- f32 GEMM, bit-identical per-output fma sequence to the proven round-3 kernel ----
// Double-buffered LDS, global_load_lds staging (no staging VGPRs, no ds_writes).
__global__ __launch_bounds__(256) void gemm_t(
    const float* __restrict__ ws, float* __restrict__ C)
{
    __shared__ __align__(16) float As[2][32][128];   // 16 KB each
    __shared__ __align__(16) float Bs[2][32][128];   // total 64 KB -> 2 blocks/CU

    const int mtile = blockIdx.x >> 2;      // ntile fastest: consecutive blocks share X panels
    const int ntile = blockIdx.x & 3;
    const int m0 = mtile * 128, n0 = ntile * 128;

    const int tid  = threadIdx.x;
    const int lane = tid & 63;
    const int wid  = tid >> 6;              // 4 waves: 2x2 grid of 64x64 wave tiles
    const int wmb  = (wid >> 1) << 6;       // 0 / 64
    const int wnb  = (wid & 1) << 6;        // 0 / 64
    const int r4   = (lane >> 3) << 2;      // 0,4,...,28
    const int c4   = (lane & 7) << 2;       // 0,4,...,28

    const float* Xp = ws + (size_t)(mtile * KTILES) * 4096;
    const float* Wp = ws + (size_t)(MTILES * KTILES + ntile * KTILES) * 4096;

    float acc[8][8];
    #pragma unroll
    for (int i = 0; i < 8; ++i)
        #pragma unroll
        for (int j = 0; j < 8; ++j) acc[i][j] = 0.f;

    auto stage = [&](int buf, int kt) {
        const float* xs = Xp + (size_t)kt * 4096 + tid * 4;
        const float* wsr = Wp + (size_t)kt * 4096 + tid * 4;
        #pragma unroll
        for (int c = 0; c < 4; ++c) {
            gload_lds16(xs + c * 1024, (char*)&As[buf][0][0] + (c * 256 + tid) * 16);
            gload_lds16(wsr + c * 1024, (char*)&Bs[buf][0][0] + (c * 256 + tid) * 16);
        }
    };

    stage(0, 0);
    __syncthreads();                        // vmcnt(0) drain: tile 0 resident

    for (int kt = 0; kt < KTILES; ++kt) {
        const int cur = kt & 1;
        if (kt + 1 < KTILES) stage(cur ^ 1, kt + 1);   // async: flies under this tile's FMAs

        #pragma unroll 8
        for (int k = 0; k < 32; ++k) {
            // each read: 8 unique contiguous addrs x 16B = all 32 banks once, 8-lane broadcast
            float4 a0 = *(const float4*)&As[cur][k][wmb + r4];
            float4 a1 = *(const float4*)&As[cur][k][wmb + 32 + r4];
            float4 b0 = *(const float4*)&Bs[cur][k][wnb + c4];
            float4 b1 = *(const float4*)&Bs[cur][k][wnb + 32 + c4];
            float a[8] = {a0.x, a0.y, a0.z, a0.w, a1.x, a1.y, a1.z, a1.w};
            float b[8] = {b0.x, b0.y, b0.z, b0.w, b1.x, b1.y, b1.z, b1.w};
            #pragma unroll
            for (int i = 0; i < 8; ++i)
                #pragma unroll
                for (int j = 0; j < 8; ++j)
                    acc[i][j] += a[i] * b[j];
        }
        __syncthreads();   // readers done + next tile's gload_lds drained (vmcnt 0)
    }

    // epilogue: rows m0+wmb+{h*32+r4+i}, cols n0+wnb+{c4.., 32+c4..}  (round-3 verbatim)
    #pragma unroll
    for (int h = 0; h < 2; ++h) {
        #pragma unroll
        for (int i = 0; i < 4; ++i) {
            const int m = m0 + wmb + h * 32 + r4 + i;
            if (m >= M_TOT) continue;
            float* cp = C + (size_t)m * COUT;
            const int col0 = n0 + wnb + c4;
            const int col1 = col0 + 32;
            const int ai = h * 4 + i;
            if (col0 < COUT)
                *(float4*)(cp + col0) = make_float4(acc[ai][0], acc[ai][1], acc[ai][2], acc[ai][3]);
            if (col1 < COUT)
                *(float4*)(cp + col1) = make_float4(acc[ai][4], acc[ai][5], acc[ai][6], acc[ai][7]);
        }
    }
}

// ---- fallback fp32 GEMM (round-3 proven, unchanged) ----
constexpr int BM = 128, BN = 128, BK = 32;
constexpr int LDA = BM + 4;

__global__ __launch_bounds__(256) void gemm_f32(
    const float* __restrict__ X, const float* __restrict__ W, float* __restrict__ C)
{
    __shared__ float As[BK][LDA];
    __shared__ float Bs[BK][LDA];

    const int mtile = blockIdx.x >> 2;
    const int ntile = blockIdx.x & 3;
    const int m0 = mtile * BM, n0 = ntile * BN;

    const int tid  = threadIdx.x;
    const int lane = tid & 63;
    const int wid  = tid >> 6;
    const int wmb  = (wid >> 1) << 6;
    const int wnb  = (wid & 1) << 6;
    const int r4   = (lane >> 3) << 2;
    const int c4   = (lane & 7) << 2;
    const int lr = tid >> 3;
    const int lk = (tid & 7) << 2;

    float acc[8][8];
    #pragma unroll
    for (int i = 0; i < 8; ++i)
        #pragma unroll
        for (int j = 0; j < 8; ++j) acc[i][j] = 0.f;

    for (int k0 = 0; k0 < CIN; k0 += BK) {
        const int kk = k0 + lk;
        const bool kv = (kk < CIN);
        #pragma unroll
        for (int p = 0; p < 4; ++p) {
            int row = p * 32 + lr;
            int m = m0 + row;
            float4 v = make_float4(0.f, 0.f, 0.f, 0.f);
            if (kv && m < M_TOT) v = *(const float4*)(X + (size_t)m * CIN + kk);
            As[lk + 0][row] = v.x; As[lk + 1][row] = v.y;
            As[lk + 2][row] = v.z; As[lk + 3][row] = v.w;
        }
        #pragma unroll
        for (int p = 0; p < 4; ++p) {
            int row = p * 32 + lr;
            int o = n0 + row;
            float4 v = make_float4(0.f, 0.f, 0.f, 0.f);
            if (kv && o < COUT) v = *(const float4*)(W + (size_t)o * CIN + kk);
            Bs[lk + 0][row] = v.x; Bs[lk + 1][row] = v.y;
            Bs[lk + 2][row] = v.z; Bs[lk + 3][row] = v.w;
        }
        __syncthreads();
        #pragma unroll 8
        for (int k = 0; k < BK; ++k) {
            float4 a0 = *(const float4*)&As[k][wmb + r4];
            float4 a1 = *(const float4*)&As[k][wmb + 32 + r4];
            float4 b0 = *(const float4*)&Bs[k][wnb + c4];
            float4 b1 = *(const float4*)&Bs[k][wnb + 32 + c4];
            float a[8] = {a0.x, a0.y, a0.z, a0.w, a1.x, a1.y, a1.z, a1.w};
            float b[8] = {b0.x, b0.y, b0.z, b0.w, b1.x, b1.y, b1.z, b1.w};
            #pragma unroll
            for (int i = 0; i < 8; ++i)
                #pragma unroll
                for (int j = 0; j < 8; ++j)
                    acc[i][j] += a[i] * b[j];
        }
        __syncthreads();
    }

    #pragma unroll
    for (int h = 0; h < 2; ++h) {
        #pragma unroll
        for (int i = 0; i < 4; ++i) {
            const int m = m0 + wmb + h * 32 + r4 + i;
            if (m >= M_TOT) continue;
            float* cp = C + (size_t)m * COUT;
            const int col0 = n0 + wnb + c4;
            const int col1 = col0 + 32;
            const int ai = h * 4 + i;
            if (col0 < COUT)
                *(float4*)(cp + col0) = make_float4(acc[ai][0], acc[ai][1], acc[ai][2], acc[ai][3]);
            if (col1 < COUT)
                *(float4*)(cp + col1) = make_float4(acc[ai][4], acc[ai][5], acc[ai][6], acc[ai][7]);
        }
    }
}

// ---- LIF scan, in place over C (identical source to all passing rounds). threshold == 1 ----
__global__ __launch_bounds__(256) void lif_scan(
    const float* __restrict__ alpha, float* __restrict__ C)
{
    const int n = blockIdx.x * blockDim.x + threadIdx.x;
    if (n >= NB * COUT) return;
    const int b = n / COUT, o = n % COUT;
    const float a = alpha[n];
    float v = 0.f;
    float* p = C + (size_t)b * NT * COUT + o;

    constexpr int U = 10;
    for (int t0 = 0; t0 < NT; t0 += U) {
        float xl[U];
        #pragma unroll
        for (int u = 0; u < U; ++u) xl[u] = p[(size_t)(t0 + u) * COUT];
        float s[U];
        #pragma unroll
        for (int u = 0; u < U; ++u) {
            float vp = a * v + xl[u];
            vp = fmaxf(vp, -1.f);
            float sp = (vp >= 1.f) ? floorf(vp) : 0.f;
            v = vp - sp;
            s[u] = sp;
        }
        #pragma unroll
        for (int u = 0; u < U; ++u) p[(size_t)(t0 + u) * COUT] = s[u];
    }
}

extern "C" void kernel_launch(void* const* d_in, const int* in_sizes, int n_in,
                              void* d_out, int out_size, void* d_ws, size_t ws_size,
                              hipStream_t stream) {
    const float* X     = (const float*)d_in[0];   // [100,500,300]
    const float* W     = (const float*)d_in[1];   // [500,300]
    const float* alpha = (const float*)d_in[2];   // [50000]
    float* C = (float*)d_out;                     // [100,500,500]

    if (ws_size >= WS_NEED && d_ws != nullptr) {
        float* ws = (float*)d_ws;
        split_t<<<dim3(NPANEL), dim3(256), 0, stream>>>(X, W, ws);
        gemm_t<<<dim3(MTILES * NTILES), dim3(256), 0, stream>>>(ws, C);
    } else {
        gemm_f32<<<dim3(MTILES * NTILES), dim3(256), 0, stream>>>(X, W, C);
    }

    const int nneur = NB * COUT;
    lif_scan<<<dim3((nneur + 255) / 256), dim3(256), 0, stream>>>(alpha, C);
}